// Round 1
// baseline (264.465 us; speedup 1.0000x reference)
//
#include <hip/hip_runtime.h>

// Problem constants (fixed by the reference)
#define BATCH   262144
#define DDIM    128
// blocks: j%3==0 dense, j%3==1 diagonal, j%3==2 lowrank; k = j/3 in all cases.

__global__ __launch_bounds__(256, 4) void bdla_kernel(
    const float* __restrict__ x,
    const float* __restrict__ Wd,   // [3,16,16]  W[k][o][d]
    const float* __restrict__ sd,   // [3,16]
    const float* __restrict__ U,    // [2,16,4]
    const float* __restrict__ V,    // [2,16,4]
    float* __restrict__ out)
{
    __shared__ float lds[1072];     // 768 Wd | 48 sd | 128 U | 128 V
    const int tid = threadIdx.x;
    for (int i = tid; i < 768; i += 256) lds[i] = Wd[i];
    if (tid < 48)  lds[768 + tid] = sd[tid];
    if (tid < 128) lds[816 + tid] = U[tid];
    if (tid < 128) lds[944 + tid] = V[tid];
    __syncthreads();

    const int lane   = tid & 63;
    const int lane32 = lane & 31;
    const int half   = lane >> 5;      // which row of the wave's pair
    const int j      = lane32 >> 2;    // block id 0..7
    const int sub    = lane32 & 3;     // quarter within block (4 outputs)
    const int mode   = j % 3;          // 0 dense, 1 diag, 2 lowrank
    const int k      = j / 3;

    // A[oo][m*4+c]: weight applied to g[m*4+c] = shfl_xor(xv.c, m),
    // i.e. block-input element d = (sub^m)*4 + c. Built once; all indices
    // into A are compile-time so it stays in VGPRs.
    float A[4][16];
    if (mode == 0) {
        const float* w = &lds[k * 256];
#pragma unroll
        for (int oo = 0; oo < 4; ++oo) {
            const int o = sub * 4 + oo;
#pragma unroll
            for (int m = 0; m < 4; ++m)
#pragma unroll
                for (int c = 0; c < 4; ++c)
                    A[oo][m * 4 + c] = w[o * 16 + ((sub ^ m) * 4 + c)];
        }
    } else if (mode == 1) {
        const float* s = &lds[768 + k * 16];
#pragma unroll
        for (int oo = 0; oo < 4; ++oo)
#pragma unroll
            for (int m = 0; m < 4; ++m)
#pragma unroll
                for (int c = 0; c < 4; ++c)
                    A[oo][m * 4 + c] = (m == 0 && c == oo) ? s[sub * 4 + oo] : 0.0f;
    } else {
        const float* u = &lds[816 + k * 64];
        const float* v = &lds[944 + k * 64];
#pragma unroll
        for (int oo = 0; oo < 4; ++oo) {
            const int o = sub * 4 + oo;
#pragma unroll
            for (int m = 0; m < 4; ++m)
#pragma unroll
                for (int c = 0; c < 4; ++c) {
                    const int d = (sub ^ m) * 4 + c;
                    float acc = 0.0f;
#pragma unroll
                    for (int r = 0; r < 4; ++r)
                        acc += u[o * 4 + r] * v[d * 4 + r];
                    A[oo][m * 4 + c] = acc;
                }
        }
    }

    const int wavesPerBlock = 256 / 64;
    const int gwave     = blockIdx.x * wavesPerBlock + (tid >> 6);
    const int rowStride = gridDim.x * wavesPerBlock * 2;

    int row = gwave * 2 + half;
    if (row >= BATCH) return;

    const float* xp = x + (size_t)row * DDIM + lane32 * 4;
    float4 xv = *(const float4*)xp;

    while (true) {
        const int nrow = row + rowStride;
        const bool has = (nrow < BATCH);
        float4 xn;
        if (has) xn = *(const float4*)(x + (size_t)nrow * DDIM + lane32 * 4);

        // gather the 16 inputs of this lane's block (4-lane group)
        float g[16];
        g[0] = xv.x; g[1] = xv.y; g[2] = xv.z; g[3] = xv.w;
        g[4]  = __shfl_xor(xv.x, 1); g[5]  = __shfl_xor(xv.y, 1);
        g[6]  = __shfl_xor(xv.z, 1); g[7]  = __shfl_xor(xv.w, 1);
        g[8]  = __shfl_xor(xv.x, 2); g[9]  = __shfl_xor(xv.y, 2);
        g[10] = __shfl_xor(xv.z, 2); g[11] = __shfl_xor(xv.w, 2);
        g[12] = __shfl_xor(xv.x, 3); g[13] = __shfl_xor(xv.y, 3);
        g[14] = __shfl_xor(xv.z, 3); g[15] = __shfl_xor(xv.w, 3);

        float y0 = 0.f, y1 = 0.f, y2 = 0.f, y3 = 0.f;
#pragma unroll
        for (int t = 0; t < 16; ++t) {
            y0 = fmaf(A[0][t], g[t], y0);
            y1 = fmaf(A[1][t], g[t], y1);
            y2 = fmaf(A[2][t], g[t], y2);
            y3 = fmaf(A[3][t], g[t], y3);
        }

        // L2 norm across the row's 32 lanes (masks < 32 stay in the half-wave)
        float ss = y0 * y0 + y1 * y1 + y2 * y2 + y3 * y3;
        ss += __shfl_xor(ss, 1);
        ss += __shfl_xor(ss, 2);
        ss += __shfl_xor(ss, 4);
        ss += __shfl_xor(ss, 8);
        ss += __shfl_xor(ss, 16);
        const float inv = 1.0f / (sqrtf(ss) + 1e-8f);

        float4 yv;
        yv.x = y0 * inv; yv.y = y1 * inv; yv.z = y2 * inv; yv.w = y3 * inv;
        *(float4*)(out + (size_t)row * DDIM + lane32 * 4) = yv;

        if (!has) break;
        row = nrow;
        xv  = xn;
    }
}

extern "C" void kernel_launch(void* const* d_in, const int* in_sizes, int n_in,
                              void* d_out, int out_size, void* d_ws, size_t ws_size,
                              hipStream_t stream) {
    const float* x  = (const float*)d_in[0];
    const float* Wd = (const float*)d_in[1];
    const float* sd = (const float*)d_in[2];
    const float* U  = (const float*)d_in[3];
    const float* V  = (const float*)d_in[4];
    float* out = (float*)d_out;
    (void)in_sizes; (void)n_in; (void)out_size; (void)d_ws; (void)ws_size;

    dim3 grid(2048), block(256);
    hipLaunchKernelGGL(bdla_kernel, grid, block, 0, stream, x, Wd, sd, U, V, out);
}

// Round 2
// 241.004 us; speedup vs baseline: 1.0973x; 1.0973x over previous
//
#include <hip/hip_runtime.h>

// Problem constants (fixed by the reference)
#define BATCH   262144
#define DDIM    128
#define GRID    2048
#define NITER   8            // BATCH / (GRID * 4 waves * 4 rows/wave/iter)
// blocks: j%3==0 dense, j%3==1 diagonal, j%3==2 lowrank; k = j/3.

__global__ __launch_bounds__(256, 3) void bdla_kernel(
    const float* __restrict__ x,
    const float* __restrict__ Wd,   // [3,16,16]  W[k][o][d]
    const float* __restrict__ sd,   // [3,16]
    const float* __restrict__ U,    // [2,16,4]
    const float* __restrict__ V,    // [2,16,4]
    float* __restrict__ out)
{
    __shared__ float lds[1072];     // 768 Wd | 48 sd | 128 U | 128 V
    const int tid = threadIdx.x;
    for (int i = tid; i < 768; i += 256) lds[i] = Wd[i];
    if (tid < 48)  lds[768 + tid] = sd[tid];
    if (tid < 128) lds[816 + tid] = U[tid];
    if (tid < 128) lds[944 + tid] = V[tid];
    __syncthreads();

    const int lane   = tid & 63;
    const int lane32 = lane & 31;
    const int half   = lane >> 5;      // which row of the wave's pair
    const int j      = lane32 >> 2;    // block id 0..7
    const int sub    = lane32 & 3;     // quarter within block (4 outputs)
    const int mode   = j % 3;          // 0 dense, 1 diag, 2 lowrank
    const int k      = j / 3;

    // A[oo][m*4+c]: weight applied to g[m*4+c] = shfl_xor(xv.c, m),
    // i.e. block-input element d = (sub^m)*4 + c.
    float A[4][16];
    if (mode == 0) {
        const float* w = &lds[k * 256];
#pragma unroll
        for (int oo = 0; oo < 4; ++oo) {
            const int o = sub * 4 + oo;
#pragma unroll
            for (int m = 0; m < 4; ++m)
#pragma unroll
                for (int c = 0; c < 4; ++c)
                    A[oo][m * 4 + c] = w[o * 16 + ((sub ^ m) * 4 + c)];
        }
    } else if (mode == 1) {
        const float* s = &lds[768 + k * 16];
#pragma unroll
        for (int oo = 0; oo < 4; ++oo)
#pragma unroll
            for (int m = 0; m < 4; ++m)
#pragma unroll
                for (int c = 0; c < 4; ++c)
                    A[oo][m * 4 + c] = (m == 0 && c == oo) ? s[sub * 4 + oo] : 0.0f;
    } else {
        const float* u = &lds[816 + k * 64];
        const float* v = &lds[944 + k * 64];
#pragma unroll
        for (int oo = 0; oo < 4; ++oo) {
            const int o = sub * 4 + oo;
#pragma unroll
            for (int m = 0; m < 4; ++m)
#pragma unroll
                for (int c = 0; c < 4; ++c) {
                    const int d = (sub ^ m) * 4 + c;
                    float acc = 0.0f;
#pragma unroll
                    for (int r = 0; r < 4; ++r)
                        acc += u[o * 4 + r] * v[d * 4 + r];
                    A[oo][m * 4 + c] = acc;
                }
        }
    }

    // Pin A into VGPRs: opaque asm def prevents the compiler from
    // rematerializing A via per-iteration LDS reads (R1: VGPR=64 proved it
    // was reloading A from LDS in the hot loop -> 5.8M bank-conflict cycles).
#pragma unroll
    for (int oo = 0; oo < 4; ++oo)
#pragma unroll
        for (int t = 0; t < 16; ++t)
            asm volatile("" : "+v"(A[oo][t]));

    // Row mapping: wave gw, iter it -> rows it*32768 + gw*4 + {half, 2+half}
    const int gw = blockIdx.x * 4 + (tid >> 6);
    const float* xbase = x   + (size_t)(gw * 4 + half) * DDIM + lane32 * 4;
    float*       obase = out + (size_t)(gw * 4 + half) * DDIM + lane32 * 4;
    const size_t istep = (size_t)(GRID * 4 * 4) * DDIM;   // floats per iter step

    // depth-2 software pipeline
    float4 a0 = *(const float4*)(xbase);
    float4 b0 = *(const float4*)(xbase + 2 * DDIM);
    float4 a1 = *(const float4*)(xbase + istep);
    float4 b1 = *(const float4*)(xbase + istep + 2 * DDIM);

#pragma unroll
    for (int it = 0; it < NITER; ++it) {
        float4 a2, b2;
        if (it + 2 < NITER) {
            a2 = *(const float4*)(xbase + (size_t)(it + 2) * istep);
            b2 = *(const float4*)(xbase + (size_t)(it + 2) * istep + 2 * DDIM);
        }

        // gather the 16 inputs of this lane's block for both rows
        float ga[16], gb[16];
        ga[0] = a0.x; ga[1] = a0.y; ga[2] = a0.z; ga[3] = a0.w;
        gb[0] = b0.x; gb[1] = b0.y; gb[2] = b0.z; gb[3] = b0.w;
#pragma unroll
        for (int m = 1; m < 4; ++m) {
            ga[m * 4 + 0] = __shfl_xor(a0.x, m);
            ga[m * 4 + 1] = __shfl_xor(a0.y, m);
            ga[m * 4 + 2] = __shfl_xor(a0.z, m);
            ga[m * 4 + 3] = __shfl_xor(a0.w, m);
            gb[m * 4 + 0] = __shfl_xor(b0.x, m);
            gb[m * 4 + 1] = __shfl_xor(b0.y, m);
            gb[m * 4 + 2] = __shfl_xor(b0.z, m);
            gb[m * 4 + 3] = __shfl_xor(b0.w, m);
        }

        float ya0 = 0.f, ya1 = 0.f, ya2 = 0.f, ya3 = 0.f;
        float yb0 = 0.f, yb1 = 0.f, yb2 = 0.f, yb3 = 0.f;
#pragma unroll
        for (int t = 0; t < 16; ++t) {
            ya0 = fmaf(A[0][t], ga[t], ya0);
            ya1 = fmaf(A[1][t], ga[t], ya1);
            ya2 = fmaf(A[2][t], ga[t], ya2);
            ya3 = fmaf(A[3][t], ga[t], ya3);
            yb0 = fmaf(A[0][t], gb[t], yb0);
            yb1 = fmaf(A[1][t], gb[t], yb1);
            yb2 = fmaf(A[2][t], gb[t], yb2);
            yb3 = fmaf(A[3][t], gb[t], yb3);
        }

        // L2 norm across each row's 32 lanes (masks < 32 stay in the half)
        float ssa = ya0 * ya0 + ya1 * ya1 + ya2 * ya2 + ya3 * ya3;
        float ssb = yb0 * yb0 + yb1 * yb1 + yb2 * yb2 + yb3 * yb3;
#pragma unroll
        for (int m = 1; m < 32; m <<= 1) {
            ssa += __shfl_xor(ssa, m);
            ssb += __shfl_xor(ssb, m);
        }
        const float inva = 1.0f / (sqrtf(ssa) + 1e-8f);
        const float invb = 1.0f / (sqrtf(ssb) + 1e-8f);

        float4 yva, yvb;
        yva.x = ya0 * inva; yva.y = ya1 * inva; yva.z = ya2 * inva; yva.w = ya3 * inva;
        yvb.x = yb0 * invb; yvb.y = yb1 * invb; yvb.z = yb2 * invb; yvb.w = yb3 * invb;
        *(float4*)(obase + (size_t)it * istep)            = yva;
        *(float4*)(obase + (size_t)it * istep + 2 * DDIM) = yvb;

        a0 = a1; b0 = b1; a1 = a2; b1 = b2;
    }
}

extern "C" void kernel_launch(void* const* d_in, const int* in_sizes, int n_in,
                              void* d_out, int out_size, void* d_ws, size_t ws_size,
                              hipStream_t stream) {
    const float* x  = (const float*)d_in[0];
    const float* Wd = (const float*)d_in[1];
    const float* sd = (const float*)d_in[2];
    const float* U  = (const float*)d_in[3];
    const float* V  = (const float*)d_in[4];
    float* out = (float*)d_out;
    (void)in_sizes; (void)n_in; (void)out_size; (void)d_ws; (void)ws_size;

    dim3 grid(GRID), block(256);
    hipLaunchKernelGGL(bdla_kernel, grid, block, 0, stream, x, Wd, sd, U, V, out);
}